// Round 10
// baseline (66.120 us; speedup 1.0000x reference)
//
#include <hip/hip_runtime.h>

#define BB 4
#define CC 64
#define C2 32            // channel pairs
#define HH 64
#define WW 64
#define PATCH 9
#define HALF 4
#define P2 81
#define HW 4096
#define IMG (CC * HW)

typedef _Float16 v2h __attribute__((ext_vector_type(2)));
typedef __fp16 v2fp __attribute__((ext_vector_type(2)));

static __device__ __forceinline__ unsigned pkrtz(float a, float b) {
    v2fp h = __builtin_amdgcn_cvt_pkrtz(a, b);   // single v_cvt_pkrtz_f16_f32
    return __builtin_bit_cast(unsigned, h);
}

// One SINGLE-WAVE block per (b, y, dy): 2304 blocks x 64 threads.
// XCD-aware decode: xcd = blockIdx % 8 owns y-octave [8*xcd, 8*xcd+8) for all
// (b, dy) -> per-XCD working set ~1.5 MB fits 4 MB L2 (9x staging redundancy
// served by L2, not HBM). f1 row in registers (f16x2), f2 row in 9.2 KB LDS.
__global__ __launch_bounds__(64) void corr_kernel(const float* __restrict__ f1,
                                                  const float* __restrict__ f2,
                                                  float* __restrict__ out) {
    __shared__ unsigned sB[C2 * 72];   // [c2][72 cols]; cols 0..3,68..71 zero (9.2 KB)
    __shared__ float sS2[64];          // f2 column inverse norms (real cols)

    const int x   = threadIdx.x;       // 0..63
    const int bid = blockIdx.x;
    const int xcd = bid & 7;
    const int s   = bid >> 3;          // 0..287
    const int b   = s / 72;
    const int r   = s - b * 72;        // 0..71
    const int yo  = r / 9;
    const int dy  = r - yo * 9;
    const int y   = xcd * 8 + yo;
    const int y2  = y + dy - HALF;

    float* ob = out + b * (P2 * HW) + y * WW + x;

    if ((unsigned)y2 >= HH) {          // whole dy-row out of bounds -> zeros
#pragma unroll
        for (int dx = 0; dx < PATCH; ++dx)
            ob[(dy * PATCH + dx) * HW] = 0.f;
        return;
    }

    // ---- issue f2 row loads first (longest dependency chain) ----
    const float* f2r = f2 + b * IMG + y2 * WW;
    float4 va[8], vb[8];
#pragma unroll
    for (int it = 0; it < 8; ++it) {
        int item = x + it * 64;        // 512 items: (c2, k)
        int c2 = item >> 4, k = item & 15;
        const float* p = f2r + 4 * k;
        va[it] = *(const float4*)(p + (2 * c2) * HW);
        vb[it] = *(const float4*)(p + (2 * c2 + 1) * HW);
    }

    // ---- f1 row -> registers (issued while f2 is in flight) ----
    const float* f1r = f1 + b * IMG + y * WW + x;
    float u[CC];
#pragma unroll
    for (int c = 0; c < CC; ++c) u[c] = f1r[c * HW];

    // ---- pack + stage f2 into LDS [c2][72], zero pads ----
#pragma unroll
    for (int it = 0; it < 8; ++it) {
        int item = x + it * 64;
        int c2 = item >> 4, k = item & 15;
        uint4 w = {pkrtz(va[it].x, vb[it].x), pkrtz(va[it].y, vb[it].y),
                   pkrtz(va[it].z, vb[it].z), pkrtz(va[it].w, vb[it].w)};
        *(uint4*)&sB[c2 * 72 + 4 + 4 * k] = w;
    }
#pragma unroll
    for (int it = 0; it < 4; ++it) {   // 256 pad dwords: cols 0..3 and 68..71
        int j = x + it * 64;
        int c2 = j >> 3, e = j & 7;
        sB[c2 * 72 + (e < 4 ? e : 64 + e)] = 0u;
    }

    // ---- pack f1 + ssq1 via fdot2 on packed values ----
    unsigned a[C2];
    float ssq1 = 0.f;
#pragma unroll
    for (int c2 = 0; c2 < C2; ++c2) {
        a[c2] = pkrtz(u[2 * c2], u[2 * c2 + 1]);
        v2h a2 = __builtin_bit_cast(v2h, a[c2]);
        ssq1 = __builtin_amdgcn_fdot2(a2, a2, ssq1, false);
    }
    __syncthreads();                   // single wave: just a waitcnt

    // ---- main loop: 32 c2 x 9 taps, v_dot2_f32_f16; f2 col ssq on the fly ----
    float acc[PATCH];
#pragma unroll
    for (int i = 0; i < PATCH; ++i) acc[i] = 0.f;
    float ssq2 = 0.f;
#pragma unroll
    for (int c2 = 0; c2 < C2; ++c2) {
        v2h a2 = __builtin_bit_cast(v2h, a[c2]);
        const unsigned* br = &sB[c2 * 72 + x];   // tap dx at padded col x+dx
#pragma unroll
        for (int dx = 0; dx < PATCH; ++dx)
            acc[dx] = __builtin_amdgcn_fdot2(a2, __builtin_bit_cast(v2h, br[dx]),
                                             acc[dx], false);
        v2h c4 = __builtin_bit_cast(v2h, br[4]); // padded col x+4 == real col x
        ssq2 = __builtin_amdgcn_fdot2(c4, c4, ssq2, false);
    }
    sS2[x] = rsqrtf(ssq2 + 1e-6f);
    __syncthreads();                   // intra-wave LDS visibility

    const float s1 = rsqrtf(ssq1 + 1e-6f);
#pragma unroll
    for (int dx = 0; dx < PATCH; ++dx) {
        int col = x + dx - HALF;
        col = min(max(col, 0), WW - 1);          // OOB taps have acc==0
        ob[(dy * PATCH + dx) * HW] = fmaxf(acc[dx] * s1 * sS2[col], 0.f);
    }
}

extern "C" void kernel_launch(void* const* d_in, const int* in_sizes, int n_in,
                              void* d_out, int out_size, void* d_ws, size_t ws_size,
                              hipStream_t stream) {
    const float* f1 = (const float*)d_in[0];
    const float* f2 = (const float*)d_in[1];
    float* out = (float*)d_out;
    (void)d_ws; (void)ws_size;

    corr_kernel<<<BB * HH * PATCH, 64, 0, stream>>>(f1, f2, out);
}